// Round 4
// baseline (5037.050 us; speedup 1.0000x reference)
//
#include <hip/hip_runtime.h>
#include <math.h>

static constexpr int BATCH = 512;
static constexpr int F = 128;
static constexpr int H = 8;
static constexpr int GH = 32;         // per-head hidden
static constexpr int NIN2 = H * GH;   // 256
static constexpr int MH = 256;        // MLP hidden
static constexpr float ALPHA = 0.2f;
static constexpr float NEGV = -9e15f;

// ---------------- kernel A: x[b][f][:] = emb[ids[b][f]] * vals[b][f] ----------------
__global__ __launch_bounds__(256) void k_embed(
    const int* __restrict__ ids, const float* __restrict__ vals,
    const float* __restrict__ emb, float* __restrict__ x)
{
  int idx = blockIdx.x * 256 + threadIdx.x;       // float4 index; total B*F*16
  int e4 = idx & 15;
  int bf = idx >> 4;
  int id = ids[bf];
  float v = vals[bf];
  float4 r = reinterpret_cast<const float4*>(emb)[(size_t)id * 16 + e4];
  r.x *= v; r.y *= v; r.z *= v; r.w *= v;
  reinterpret_cast<float4*>(x)[idx] = r;
}

// ---------------- generic fp32 GEMM: out[kc][M][256] = A[M][K] @ B[K][256] ----------
// BGAT=0: B plain row-major [K][256].  BGAT=1: B = W[H][K][GH] gather, col c=(h*32+o).
// Grid: x = M/64 row tiles, y = 2 col tiles (128), z = KC K-splits; KCHUNK = K/KC.
// Per thread: 8 rows x 4 cols = 32 accumulators (no spill; R3's k_mlp1 spilled 64).
template <int BGAT>
__global__ __launch_bounds__(256, 4) void k_gemm(
    const float* __restrict__ A, const float* __restrict__ B,
    float* __restrict__ out, int M, int K, int KCHUNK)
{
  const int rt = blockIdx.x, ct = blockIdx.y, kc = blockIdx.z;
  const int t = threadIdx.x;
  __shared__ float At[64 * 36];    // [row][k32] pad 36
  __shared__ float Bt[32 * 132];   // [k32][col128] pad 132
  const int r0 = rt * 64, c0 = ct * 128, k0 = kc * KCHUNK;
  const int tc = t & 31;           // col group: cols c0 + tc*4 ..+3
  const int tr = t >> 5;           // row group: rows r0 + tr*8 ..+7
  float acc[8][4] = {};

  const int nkt = KCHUNK >> 5;
  for (int kt = 0; kt < nkt; kt++) {
    const int kb = k0 + kt * 32;
#pragma unroll
    for (int q = 0; q < 2; q++) {                 // stage A: 64x32 = 512 float4
      int idx = q * 256 + t;
      int rr = idx >> 3, cc = (idx & 7) * 4;
      *(float4*)&At[rr * 36 + cc] =
          *(const float4*)(A + (size_t)(r0 + rr) * K + kb + cc);
    }
#pragma unroll
    for (int q = 0; q < 4; q++) {                 // stage B: 32x128 = 1024 float4
      int idx = q * 256 + t;
      int kk = idx >> 5, cc = (idx & 31) * 4;
      int c = c0 + cc;
      float4 v;
      if (BGAT)
        v = *(const float4*)(B + (size_t)(c >> 5) * K * GH + (size_t)(kb + kk) * GH + (c & 31));
      else
        v = *(const float4*)(B + (size_t)(kb + kk) * 256 + c);
      *(float4*)&Bt[kk * 132 + cc] = v;
    }
    __syncthreads();
#pragma unroll
    for (int kq = 0; kq < 8; kq++) {
      const int kk = kq * 4;
      float4 b0 = *(const float4*)&Bt[(kk + 0) * 132 + tc * 4];
      float4 b1 = *(const float4*)&Bt[(kk + 1) * 132 + tc * 4];
      float4 b2 = *(const float4*)&Bt[(kk + 2) * 132 + tc * 4];
      float4 b3 = *(const float4*)&Bt[(kk + 3) * 132 + tc * 4];
#pragma unroll
      for (int r = 0; r < 8; r++) {
        float4 a = *(const float4*)&At[(tr * 8 + r) * 36 + kk];   // 2-addr broadcast/wave
        acc[r][0] += a.x * b0.x + a.y * b1.x + a.z * b2.x + a.w * b3.x;
        acc[r][1] += a.x * b0.y + a.y * b1.y + a.z * b2.y + a.w * b3.y;
        acc[r][2] += a.x * b0.z + a.y * b1.z + a.z * b2.z + a.w * b3.z;
        acc[r][3] += a.x * b0.w + a.y * b1.w + a.z * b2.w + a.w * b3.w;
      }
    }
    __syncthreads();
  }
  float* pp = out + ((size_t)kc * M + r0 + tr * 8) * 256 + c0 + tc * 4;
#pragma unroll
  for (int r = 0; r < 8; r++)
    *(float4*)(pp + (size_t)r * 256) = make_float4(acc[r][0], acc[r][1], acc[r][2], acc[r][3]);
}

// ---------------- attention kernel: one block per (b, head) ----------------
// Reads precomputed hWall[b][f][h*32+o]; computes si/sj, score+softmax+PV (logic
// carried from the verified R3 k_gat phase 2), writes elu'd output.
__global__ __launch_bounds__(256, 2) void k_attn(
    const float* __restrict__ hWall,  // [B][F][256]
    const float* __restrict__ ag,     // [H][2*GH]
    const float* __restrict__ adj,    // [F][F]
    float* __restrict__ hout)         // [B][F][256]
{
  const int b = blockIdx.x >> 3, h = blockIdx.x & 7;
  const int t = threadIdx.x;
  __shared__ float hWt[128 * 36];
  __shared__ float P[128 * 68];       // col-major: P[j][il], il = row within 64-half
  __shared__ float sil[128], sjl[128], invl[64], al[64];

  if (t < 64) al[t] = ag[h * 64 + t];
  const float* src = hWall + ((size_t)b * F) * 256 + h * 32;
#pragma unroll
  for (int q = 0; q < 4; q++) {       // stage hW tile 128x32
    int idx = q * 256 + t;
    int rr = idx >> 3, cc = (idx & 7) * 4;
    *(float4*)&hWt[rr * 36 + cc] = *(const float4*)(src + (size_t)rr * 256 + cc);
  }
  __syncthreads();

  { // si/sj: 2 threads per row, 16 cols each
    const int i = t >> 1, half = t & 1;
    const float* hr = &hWt[i * 36 + half * 16];
    const float* a0 = &al[half * 16];
    const float* a1 = &al[32 + half * 16];
    float si = 0.f, sj = 0.f;
#pragma unroll
    for (int q = 0; q < 4; q++) {
      float4 hv = *(const float4*)(hr + q * 4);
      float4 av = *(const float4*)(a0 + q * 4);
      float4 bv = *(const float4*)(a1 + q * 4);
      si += hv.x * av.x + hv.y * av.y + hv.z * av.z + hv.w * av.w;
      sj += hv.x * bv.x + hv.y * bv.y + hv.z * bv.z + hv.w * bv.w;
    }
    si += __shfl_xor(si, 1);
    sj += __shfl_xor(sj, 1);
    if (half == 0) { sil[i] = si; sjl[i] = sj; }
  }
  __syncthreads();

  for (int rh = 0; rh < 2; rh++) {
    { // score pass: 4 threads per row, thread covers j = 4*jj + l
      const int il = t >> 2, i = rh * 64 + il, l = t & 3;
      const float si = sil[i];
      float mx = -INFINITY;
#pragma unroll
      for (int jj = 0; jj < 32; jj++) {
        int j = jj * 4 + l;
        float e = si + sjl[j];
        e = e > 0.f ? e : ALPHA * e;
        float m = adj[i * F + j];
        m = m > 0.f ? m : NEGV;
        float s = e * m;
        P[j * 68 + il] = s;
        mx = fmaxf(mx, s);
      }
      mx = fmaxf(mx, __shfl_xor(mx, 1));
      mx = fmaxf(mx, __shfl_xor(mx, 2));
      float sum = 0.f;
#pragma unroll
      for (int jj = 0; jj < 32; jj++) {
        int j = jj * 4 + l;
        float p = __expf(P[j * 68 + il] - mx);
        P[j * 68 + il] = p;             // unnormalized; 1/sum folded into epilogue
        sum += p;
      }
      sum += __shfl_xor(sum, 1);
      sum += __shfl_xor(sum, 2);
      if (l == 0) invl[il] = 1.f / sum;
    }
    __syncthreads();

    { // PV: 1 row x 8 cols per thread; P reads broadcast over 4 col-lanes
      const int rr = t >> 2, cg = t & 3;
      float o0[4] = {}, o1[4] = {};
      const float* hWo = &hWt[cg * 8];
      const float* Pr = &P[rr];
#pragma unroll 2
      for (int j = 0; j < 128; j++) {
        float p = Pr[j * 68];
        float4 w0 = *(const float4*)&hWo[j * 36];
        float4 w1 = *(const float4*)&hWo[j * 36 + 4];
        o0[0] += p * w0.x; o0[1] += p * w0.y; o0[2] += p * w0.z; o0[3] += p * w0.w;
        o1[0] += p * w1.x; o1[1] += p * w1.y; o1[2] += p * w1.z; o1[3] += p * w1.w;
      }
      const float inv = invl[rr];
      float* po = hout + ((size_t)b * F + rh * 64 + rr) * 256 + h * GH + cg * 8;
      float4 v0, v1;
      float* p0 = &v0.x;
      float* p1 = &v1.x;
#pragma unroll
      for (int c = 0; c < 4; c++) {
        float xa = o0[c] * inv; p0[c] = xa > 0.f ? xa : expm1f(xa);
        float xb = o1[c] * inv; p1[c] = xb > 0.f ? xb : expm1f(xb);
      }
      *(float4*)po = v0;
      *(float4*)(po + 4) = v1;
    }
    __syncthreads();
  }
}

// ---------------- kernel D: reduce partials + bias/relu + MLP2 + output ----------------
__global__ __launch_bounds__(256) void k_mlp2(
    const float* __restrict__ part, const float* __restrict__ b0,
    const float* __restrict__ w1, const float* __restrict__ b1,
    const float* __restrict__ ow, const float* __restrict__ ob,
    float* __restrict__ y)
{
  const int b = blockIdx.x;        // 0..511
  const int t = threadIdx.x;       // col
  __shared__ float z1[MH];
  __shared__ float red[4];

  float s = b0[t];
  for (int kc = 0; kc < 64; kc++)
    s += part[((size_t)kc * 512 + b) * 256 + t];
  z1[t] = fmaxf(s, 0.f);
  __syncthreads();

  float s2 = b1[t];
  for (int k = 0; k < 256; k += 4) {
    float4 z4 = *reinterpret_cast<const float4*>(&z1[k]);
    s2 += z4.x * w1[(k + 0) * 256 + t] + z4.y * w1[(k + 1) * 256 + t]
        + z4.z * w1[(k + 2) * 256 + t] + z4.w * w1[(k + 3) * 256 + t];
  }
  s2 = fmaxf(s2, 0.f);

  float p = s2 * ow[t];
#pragma unroll
  for (int d = 1; d < 64; d <<= 1) p += __shfl_xor(p, d);
  if ((t & 63) == 0) red[t >> 6] = p;
  __syncthreads();
  if (t == 0) y[b] = red[0] + red[1] + red[2] + red[3] + ob[0];
}

extern "C" void kernel_launch(void* const* d_in, const int* in_sizes, int n_in,
                              void* d_out, int out_size, void* d_ws, size_t ws_size,
                              hipStream_t stream) {
  const int*   ids  = (const int*)  d_in[0];
  const float* vals = (const float*)d_in[1];
  const float* adj  = (const float*)d_in[2];
  const float* emb  = (const float*)d_in[3];
  const float* W0   = (const float*)d_in[4];
  const float* a0   = (const float*)d_in[5];
  const float* W1   = (const float*)d_in[6];
  const float* a1   = (const float*)d_in[7];
  const float* mw0  = (const float*)d_in[8];
  const float* mb0  = (const float*)d_in[9];
  const float* mw1  = (const float*)d_in[10];
  const float* mb1  = (const float*)d_in[11];
  const float* ow   = (const float*)d_in[12];
  const float* ob   = (const float*)d_in[13];
  float* out = (float*)d_out;

  // ws layout (floats), lifetime-audited:
  //   x    @ 0          (4,194,304)   dead after k_gemm<1> #1
  //   hW1  @ 4,194,304  (16,777,216)  dead after k_attn #1
  //   h1   @ 20,971,520 (16,777,216)  dead after k_gemm<1> #2
  //   hW2  @ 0          (16,777,216)  overlays x+hW1; dead after k_attn #2
  //   h2   @ 20,971,520              overlays h1
  //   part @ 0          (8,388,608)   overlays hW2
  float* ws = (float*)d_ws;
  float* x    = ws;
  float* hW1  = ws + 4194304;
  float* h1   = ws + 20971520;
  float* hW2  = ws;
  float* h2   = ws + 20971520;
  float* part = ws;

  k_embed<<<4096, 256, 0, stream>>>(ids, vals, emb, x);
  k_gemm<1><<<dim3(1024, 2, 1), 256, 0, stream>>>(x,  W0,  hW1, BATCH * F, 64, 64);
  k_attn   <<<BATCH * H, 256, 0, stream>>>(hW1, a0, adj, h1);
  k_gemm<1><<<dim3(1024, 2, 1), 256, 0, stream>>>(h1, W1,  hW2, BATCH * F, 256, 256);
  k_attn   <<<BATCH * H, 256, 0, stream>>>(hW2, a1, adj, h2);
  k_gemm<0><<<dim3(8, 2, 64), 256, 0, stream>>>(h2, mw0, part, 512, 32768, 512);
  k_mlp2<<<BATCH, 256, 0, stream>>>(part, mb0, mw1, mb1, ow, ob, out);
}

// Round 12
// 2422.450 us; speedup vs baseline: 2.0793x; 2.0793x over previous
//
#include <hip/hip_runtime.h>
#include <math.h>

static constexpr int BATCH = 512;
static constexpr int F = 128;
static constexpr int H = 8;
static constexpr int GH = 32;         // per-head hidden
static constexpr int NIN2 = H * GH;   // 256
static constexpr int MH = 256;        // MLP hidden
static constexpr float ALPHA = 0.2f;
static constexpr float NEGV = -9e15f;

// SESSION RULE #1 (R1/R3/R4 evidence): hipcc caps VGPRs at 256/<second
// __launch_bounds__ arg>: (256,2)->128, (256,4)->64. A 32-accumulator GEMM
// under a 64-reg cap spills to scratch -> GBs of HBM RMW churn. Never use
// (256,4) on accumulator-heavy kernels.

// ---------------- kernel A: x[b][f][:] = emb[ids[b][f]] * vals[b][f] ----------------
__global__ __launch_bounds__(256) void k_embed(
    const int* __restrict__ ids, const float* __restrict__ vals,
    const float* __restrict__ emb, float* __restrict__ x)
{
  int idx = blockIdx.x * 256 + threadIdx.x;       // float4 index; total B*F*16
  int e4 = idx & 15;
  int bf = idx >> 4;
  int id = ids[bf];
  float v = vals[bf];
  float4 r = reinterpret_cast<const float4*>(emb)[(size_t)id * 16 + e4];
  r.x *= v; r.y *= v; r.z *= v; r.w *= v;
  reinterpret_cast<float4*>(x)[idx] = r;
}

// ---------------- generic fp32 GEMM: out[kc][M][256] = A[M][K] @ B[K][256] ----------
// BGAT=0: B plain row-major [K][256].  BGAT=1: B = W[H][K][GH] gather, col c=(h*32+o).
// Grid: x = M/64 row tiles, y = 2 col tiles (128), z = KC K-splits; KCHUNK = K/KC.
// Per thread: 8 rows x 4 cols = 32 accumulators. 128-reg cap -> no spill.
template <int BGAT>
__global__ __launch_bounds__(256, 2) void k_gemm(
    const float* __restrict__ A, const float* __restrict__ B,
    float* __restrict__ out, int M, int K, int KCHUNK)
{
  const int rt = blockIdx.x, ct = blockIdx.y, kc = blockIdx.z;
  const int t = threadIdx.x;
  __shared__ float At[64 * 36];    // [row][k32] pad 36
  __shared__ float Bt[32 * 132];   // [k32][col128] pad 132
  const int r0 = rt * 64, c0 = ct * 128, k0 = kc * KCHUNK;
  const int tc = t & 31;           // col group: cols c0 + tc*4 ..+3
  const int tr = t >> 5;           // row group: rows r0 + tr*8 ..+7
  float acc[8][4] = {};

  const int nkt = KCHUNK >> 5;
  for (int kt = 0; kt < nkt; kt++) {
    const int kb = k0 + kt * 32;
#pragma unroll
    for (int q = 0; q < 2; q++) {                 // stage A: 64x32 = 512 float4
      int idx = q * 256 + t;
      int rr = idx >> 3, cc = (idx & 7) * 4;
      *(float4*)&At[rr * 36 + cc] =
          *(const float4*)(A + (size_t)(r0 + rr) * K + kb + cc);
    }
#pragma unroll
    for (int q = 0; q < 4; q++) {                 // stage B: 32x128 = 1024 float4
      int idx = q * 256 + t;
      int kk = idx >> 5, cc = (idx & 31) * 4;
      int c = c0 + cc;
      float4 v;
      if (BGAT)
        v = *(const float4*)(B + (size_t)(c >> 5) * K * GH + (size_t)(kb + kk) * GH + (c & 31));
      else
        v = *(const float4*)(B + (size_t)(kb + kk) * 256 + c);
      *(float4*)&Bt[kk * 132 + cc] = v;
    }
    __syncthreads();
#pragma unroll
    for (int kq = 0; kq < 8; kq++) {
      const int kk = kq * 4;
      float4 b0 = *(const float4*)&Bt[(kk + 0) * 132 + tc * 4];
      float4 b1 = *(const float4*)&Bt[(kk + 1) * 132 + tc * 4];
      float4 b2 = *(const float4*)&Bt[(kk + 2) * 132 + tc * 4];
      float4 b3 = *(const float4*)&Bt[(kk + 3) * 132 + tc * 4];
#pragma unroll
      for (int r = 0; r < 8; r++) {
        float4 a = *(const float4*)&At[(tr * 8 + r) * 36 + kk];   // 2-addr broadcast/wave
        acc[r][0] += a.x * b0.x + a.y * b1.x + a.z * b2.x + a.w * b3.x;
        acc[r][1] += a.x * b0.y + a.y * b1.y + a.z * b2.y + a.w * b3.y;
        acc[r][2] += a.x * b0.z + a.y * b1.z + a.z * b2.z + a.w * b3.z;
        acc[r][3] += a.x * b0.w + a.y * b1.w + a.z * b2.w + a.w * b3.w;
      }
    }
    __syncthreads();
  }
  float* pp = out + ((size_t)kc * M + r0 + tr * 8) * 256 + c0 + tc * 4;
#pragma unroll
  for (int r = 0; r < 8; r++)
    *(float4*)(pp + (size_t)r * 256) = make_float4(acc[r][0], acc[r][1], acc[r][2], acc[r][3]);
}

// ---------------- attention kernel: one block per (b, head) ----------------
// Reads precomputed hWall[b][f][h*32+o]; computes si/sj, score+softmax+PV (logic
// carried from the verified R3 k_gat phase 2), writes elu'd output.
__global__ __launch_bounds__(256, 2) void k_attn(
    const float* __restrict__ hWall,  // [B][F][256]
    const float* __restrict__ ag,     // [H][2*GH]
    const float* __restrict__ adj,    // [F][F]
    float* __restrict__ hout)         // [B][F][256]
{
  const int b = blockIdx.x >> 3, h = blockIdx.x & 7;
  const int t = threadIdx.x;
  __shared__ float hWt[128 * 36];
  __shared__ float P[128 * 68];       // col-major: P[j][il], il = row within 64-half
  __shared__ float sil[128], sjl[128], invl[64], al[64];

  if (t < 64) al[t] = ag[h * 64 + t];
  const float* src = hWall + ((size_t)b * F) * 256 + h * 32;
#pragma unroll
  for (int q = 0; q < 4; q++) {       // stage hW tile 128x32
    int idx = q * 256 + t;
    int rr = idx >> 3, cc = (idx & 7) * 4;
    *(float4*)&hWt[rr * 36 + cc] = *(const float4*)(src + (size_t)rr * 256 + cc);
  }
  __syncthreads();

  { // si/sj: 2 threads per row, 16 cols each
    const int i = t >> 1, half = t & 1;
    const float* hr = &hWt[i * 36 + half * 16];
    const float* a0 = &al[half * 16];
    const float* a1 = &al[32 + half * 16];
    float si = 0.f, sj = 0.f;
#pragma unroll
    for (int q = 0; q < 4; q++) {
      float4 hv = *(const float4*)(hr + q * 4);
      float4 av = *(const float4*)(a0 + q * 4);
      float4 bv = *(const float4*)(a1 + q * 4);
      si += hv.x * av.x + hv.y * av.y + hv.z * av.z + hv.w * av.w;
      sj += hv.x * bv.x + hv.y * bv.y + hv.z * bv.z + hv.w * bv.w;
    }
    si += __shfl_xor(si, 1);
    sj += __shfl_xor(sj, 1);
    if (half == 0) { sil[i] = si; sjl[i] = sj; }
  }
  __syncthreads();

  for (int rh = 0; rh < 2; rh++) {
    { // score pass: 4 threads per row, thread covers j = 4*jj + l
      const int il = t >> 2, i = rh * 64 + il, l = t & 3;
      const float si = sil[i];
      float mx = -INFINITY;
#pragma unroll
      for (int jj = 0; jj < 32; jj++) {
        int j = jj * 4 + l;
        float e = si + sjl[j];
        e = e > 0.f ? e : ALPHA * e;
        float m = adj[i * F + j];
        m = m > 0.f ? m : NEGV;
        float s = e * m;
        P[j * 68 + il] = s;
        mx = fmaxf(mx, s);
      }
      mx = fmaxf(mx, __shfl_xor(mx, 1));
      mx = fmaxf(mx, __shfl_xor(mx, 2));
      float sum = 0.f;
#pragma unroll
      for (int jj = 0; jj < 32; jj++) {
        int j = jj * 4 + l;
        float p = __expf(P[j * 68 + il] - mx);
        P[j * 68 + il] = p;             // unnormalized; 1/sum folded into epilogue
        sum += p;
      }
      sum += __shfl_xor(sum, 1);
      sum += __shfl_xor(sum, 2);
      if (l == 0) invl[il] = 1.f / sum;
    }
    __syncthreads();

    { // PV: 1 row x 8 cols per thread; P reads broadcast over 4 col-lanes
      const int rr = t >> 2, cg = t & 3;
      float o0[4] = {}, o1[4] = {};
      const float* hWo = &hWt[cg * 8];
      const float* Pr = &P[rr];
#pragma unroll 2
      for (int j = 0; j < 128; j++) {
        float p = Pr[j * 68];
        float4 w0 = *(const float4*)&hWo[j * 36];
        float4 w1 = *(const float4*)&hWo[j * 36 + 4];
        o0[0] += p * w0.x; o0[1] += p * w0.y; o0[2] += p * w0.z; o0[3] += p * w0.w;
        o1[0] += p * w1.x; o1[1] += p * w1.y; o1[2] += p * w1.z; o1[3] += p * w1.w;
      }
      const float inv = invl[rr];
      float* po = hout + ((size_t)b * F + rh * 64 + rr) * 256 + h * GH + cg * 8;
      float4 v0, v1;
      float* p0 = &v0.x;
      float* p1 = &v1.x;
#pragma unroll
      for (int c = 0; c < 4; c++) {
        float xa = o0[c] * inv; p0[c] = xa > 0.f ? xa : expm1f(xa);
        float xb = o1[c] * inv; p1[c] = xb > 0.f ? xb : expm1f(xb);
      }
      *(float4*)po = v0;
      *(float4*)(po + 4) = v1;
    }
    __syncthreads();
  }
}

// ---------------- kernel D: reduce partials + bias/relu + MLP2 + output ----------------
__global__ __launch_bounds__(256) void k_mlp2(
    const float* __restrict__ part, const float* __restrict__ b0,
    const float* __restrict__ w1, const float* __restrict__ b1,
    const float* __restrict__ ow, const float* __restrict__ ob,
    float* __restrict__ y)
{
  const int b = blockIdx.x;        // 0..511
  const int t = threadIdx.x;       // col
  __shared__ float z1[MH];
  __shared__ float red[4];

  float s = b0[t];
  for (int kc = 0; kc < 64; kc++)
    s += part[((size_t)kc * 512 + b) * 256 + t];
  z1[t] = fmaxf(s, 0.f);
  __syncthreads();

  float s2 = b1[t];
  for (int k = 0; k < 256; k += 4) {
    float4 z4 = *reinterpret_cast<const float4*>(&z1[k]);
    s2 += z4.x * w1[(k + 0) * 256 + t] + z4.y * w1[(k + 1) * 256 + t]
        + z4.z * w1[(k + 2) * 256 + t] + z4.w * w1[(k + 3) * 256 + t];
  }
  s2 = fmaxf(s2, 0.f);

  float p = s2 * ow[t];
#pragma unroll
  for (int d = 1; d < 64; d <<= 1) p += __shfl_xor(p, d);
  if ((t & 63) == 0) red[t >> 6] = p;
  __syncthreads();
  if (t == 0) y[b] = red[0] + red[1] + red[2] + red[3] + ob[0];
}

extern "C" void kernel_launch(void* const* d_in, const int* in_sizes, int n_in,
                              void* d_out, int out_size, void* d_ws, size_t ws_size,
                              hipStream_t stream) {
  const int*   ids  = (const int*)  d_in[0];
  const float* vals = (const float*)d_in[1];
  const float* adj  = (const float*)d_in[2];
  const float* emb  = (const float*)d_in[3];
  const float* W0   = (const float*)d_in[4];
  const float* a0   = (const float*)d_in[5];
  const float* W1   = (const float*)d_in[6];
  const float* a1   = (const float*)d_in[7];
  const float* mw0  = (const float*)d_in[8];
  const float* mb0  = (const float*)d_in[9];
  const float* mw1  = (const float*)d_in[10];
  const float* mb1  = (const float*)d_in[11];
  const float* ow   = (const float*)d_in[12];
  const float* ob   = (const float*)d_in[13];
  float* out = (float*)d_out;

  // ws layout (floats), lifetime-audited:
  //   x    @ 0          (4,194,304)   dead after k_gemm<1> #1
  //   hW1  @ 4,194,304  (16,777,216)  dead after k_attn #1
  //   h1   @ 20,971,520 (16,777,216)  dead after k_gemm<1> #2
  //   hW2  @ 0          (16,777,216)  overlays x+hW1; dead after k_attn #2
  //   h2   @ 20,971,520              overlays h1
  //   part @ 0          (8,388,608)   overlays hW2
  float* ws = (float*)d_ws;
  float* x    = ws;
  float* hW1  = ws + 4194304;
  float* h1   = ws + 20971520;
  float* hW2  = ws;
  float* h2   = ws + 20971520;
  float* part = ws;

  k_embed<<<4096, 256, 0, stream>>>(ids, vals, emb, x);
  k_gemm<1><<<dim3(1024, 2, 1), 256, 0, stream>>>(x,  W0,  hW1, BATCH * F, 64, 64);
  k_attn   <<<BATCH * H, 256, 0, stream>>>(hW1, a0, adj, h1);
  k_gemm<1><<<dim3(1024, 2, 1), 256, 0, stream>>>(h1, W1,  hW2, BATCH * F, 256, 256);
  k_attn   <<<BATCH * H, 256, 0, stream>>>(hW2, a1, adj, h2);
  k_gemm<0><<<dim3(8, 2, 64), 256, 0, stream>>>(h2, mw0, part, 512, 32768, 512);
  k_mlp2<<<BATCH, 256, 0, stream>>>(part, mb0, mw1, mb1, ow, ob, out);
}